// Round 3
// baseline (2306.925 us; speedup 1.0000x reference)
//
#include <hip/hip_runtime.h>

#define EPSF 1e-9f

typedef short bf16x8 __attribute__((ext_vector_type(8)));
typedef float f32x4 __attribute__((ext_vector_type(4)));

// round-to-nearest-even fp32 -> bf16 (bits)
__device__ inline unsigned short bf16_rne(float x) {
    unsigned u = __float_as_uint(x);
    return (unsigned short)((u + 0x7FFFu + ((u >> 16) & 1u)) >> 16);
}

// ---------------------------------------------------------------------------
// MFMA GEMM: C[M,N] = A[M,K] * B[N,K]^T (+ bias[n]).  fp32 in/out.
// Internally split-bf16: a = ah + al, b = bh + bl;  C ~= Ah*Bh + Ah*Bl + Al*Bh
// (error ~4e-6 relative; Al*Bl dropped).
// 128x128 tile, BK=32, 256 threads = 4 waves (2x2), 64x64 per wave,
// mfma_f32_16x16x32_bf16, 48 MFMA / K-step.  Requires K%32==0, N%128==0.
// ---------------------------------------------------------------------------
template <bool HAS_BIAS>
__global__ __launch_bounds__(256) void gemm_nt_mfma(const float* __restrict__ A,
                                                    const float* __restrict__ B,
                                                    const float* __restrict__ bias,
                                                    float* __restrict__ C,
                                                    int M, int N, int K) {
    __shared__ unsigned short Ah[128][32];
    __shared__ unsigned short Al[128][32];
    __shared__ unsigned short Bh[128][32];
    __shared__ unsigned short Bl[128][32];

    const int tid = threadIdx.x;
    const int lane = tid & 63;
    const int wave = tid >> 6;
    const int wr = wave >> 1;  // wave row (0..1)
    const int wc = wave & 1;   // wave col (0..1)
    const int brow = blockIdx.y * 128;
    const int bcol = blockIdx.x * 128;

    f32x4 acc[4][4] = {};

    // staging geometry: 128x32 fp32 tile = 16 floats/thread = 4x float4
    const int lrow = tid >> 3;        // 0..31 (row within a 32-row chunk)
    const int lcol = (tid & 7) * 4;   // 0..28 step 4

    float4 sa[4], sb[4];

    // ---- prologue: issue loads for tile 0 ----
#pragma unroll
    for (int it = 0; it < 4; ++it) {
        int row = it * 32 + lrow;
        int ar = min(brow + row, M - 1);
        float4 va = *(const float4*)(A + (size_t)ar * K + lcol);
        if (brow + row >= M) va = make_float4(0.f, 0.f, 0.f, 0.f);
        sa[it] = va;
        sb[it] = *(const float4*)(B + (size_t)(bcol + row) * K + lcol);
    }

    const int nt = K / 32;
    const int fr = lane & 15;
    const int fk = (lane >> 4) * 8;

    for (int t = 0; t < nt; ++t) {
        __syncthreads();  // previous MFMA phase done; LDS free
        // ---- convert + write LDS ----
#pragma unroll
        for (int it = 0; it < 4; ++it) {
            int row = it * 32 + lrow;
            const float* pv = (const float*)&sa[it];
            const float* pw = (const float*)&sb[it];
#pragma unroll
            for (int q = 0; q < 4; ++q) {
                float x = pv[q];
                unsigned short h = bf16_rne(x);
                float hf = __uint_as_float((unsigned)h << 16);
                Ah[row][lcol + q] = h;
                Al[row][lcol + q] = bf16_rne(x - hf);
            }
#pragma unroll
            for (int q = 0; q < 4; ++q) {
                float x = pw[q];
                unsigned short h = bf16_rne(x);
                float hf = __uint_as_float((unsigned)h << 16);
                Bh[row][lcol + q] = h;
                Bl[row][lcol + q] = bf16_rne(x - hf);
            }
        }
        __syncthreads();
        // ---- issue next tile's global loads (hide HBM under MFMA) ----
        if (t + 1 < nt) {
            int k0 = (t + 1) * 32;
#pragma unroll
            for (int it = 0; it < 4; ++it) {
                int row = it * 32 + lrow;
                int ar = min(brow + row, M - 1);
                float4 va = *(const float4*)(A + (size_t)ar * K + k0 + lcol);
                if (brow + row >= M) va = make_float4(0.f, 0.f, 0.f, 0.f);
                sa[it] = va;
                sb[it] = *(const float4*)(B + (size_t)(bcol + row) * K + k0 + lcol);
            }
        }
        // ---- fragments + MFMA ----
        bf16x8 fah[4], fal[4], fbh[4], fbl[4];
#pragma unroll
        for (int i = 0; i < 4; ++i) {
            int r = wr * 64 + i * 16 + fr;
            fah[i] = *(const bf16x8*)&Ah[r][fk];
            fal[i] = *(const bf16x8*)&Al[r][fk];
            int c = wc * 64 + i * 16 + fr;
            fbh[i] = *(const bf16x8*)&Bh[c][fk];
            fbl[i] = *(const bf16x8*)&Bl[c][fk];
        }
#pragma unroll
        for (int i = 0; i < 4; ++i)
#pragma unroll
            for (int j = 0; j < 4; ++j) {
                acc[i][j] = __builtin_amdgcn_mfma_f32_16x16x32_bf16(fal[i], fbh[j], acc[i][j], 0, 0, 0);
                acc[i][j] = __builtin_amdgcn_mfma_f32_16x16x32_bf16(fah[i], fbl[j], acc[i][j], 0, 0, 0);
                acc[i][j] = __builtin_amdgcn_mfma_f32_16x16x32_bf16(fah[i], fbh[j], acc[i][j], 0, 0, 0);
            }
    }

    // ---- epilogue: C/D layout col=lane&15, row=(lane>>4)*4+reg  (m89/m91) ----
    const int fq = lane >> 4;
#pragma unroll
    for (int i = 0; i < 4; ++i) {
#pragma unroll
        for (int r = 0; r < 4; ++r) {
            int grow = brow + wr * 64 + i * 16 + fq * 4 + r;
            if (grow >= M) continue;
#pragma unroll
            for (int j = 0; j < 4; ++j) {
                int gcol = bcol + wc * 64 + j * 16 + fr;
                float v = acc[i][j][r];
                if (HAS_BIAS) v += bias[gcol];
                C[(size_t)grow * N + gcol] = v;
            }
        }
    }
}

// ---------------------------------------------------------------------------
// Scores + softmax + mask + renorm (fp32-exact).  One block = (b,h,16 rows).
// ---------------------------------------------------------------------------
__global__ __launch_bounds__(256) void attn_scores(
    const float* __restrict__ Q,   // [B*L, H*64]
    const float* __restrict__ Kp,  // [S,   H*64]
    const int* __restrict__ mask,  // [B, L]
    float* __restrict__ Aout,      // [B*H*L, S]
    int B, int L, int S, int H) {
    __shared__ float sc[16][1000];
    __shared__ float facs[16];

    const int blk = blockIdx.x;
    const int lt = blk & 15;
    const int h = (blk >> 4) & 15;
    const int b = blk >> 8;
    const int l0 = lt * 16;
    const int tid = threadIdx.x;
    const float scale = 0.125f;  // 1/sqrt(64)

    const int sl = tid & 63;
    const int rg = tid >> 6;
    const float* qbase = Q + ((size_t)(b * L + l0 + rg * 4)) * 1024 + h * 64;

    for (int s0 = 0; s0 < S; s0 += 64) {
        int s = s0 + sl;
        if (s < S) {
            const float* krow = Kp + (size_t)s * 1024 + h * 64;
            float a0 = 0.f, a1 = 0.f, a2 = 0.f, a3 = 0.f;
#pragma unroll
            for (int e = 0; e < 64; e += 4) {
                float4 k4 = *(const float4*)(krow + e);
                float4 qa = *(const float4*)(qbase + e);
                float4 qb = *(const float4*)(qbase + 1024 + e);
                float4 qc = *(const float4*)(qbase + 2048 + e);
                float4 qd = *(const float4*)(qbase + 3072 + e);
                a0 += qa.x * k4.x + qa.y * k4.y + qa.z * k4.z + qa.w * k4.w;
                a1 += qb.x * k4.x + qb.y * k4.y + qb.z * k4.z + qb.w * k4.w;
                a2 += qc.x * k4.x + qc.y * k4.y + qc.z * k4.z + qc.w * k4.w;
                a3 += qd.x * k4.x + qd.y * k4.y + qd.z * k4.z + qd.w * k4.w;
            }
            sc[rg * 4 + 0][s] = a0 * scale;
            sc[rg * 4 + 1][s] = a1 * scale;
            sc[rg * 4 + 2][s] = a2 * scale;
            sc[rg * 4 + 3][s] = a3 * scale;
        }
    }
    __syncthreads();

    const int r = tid >> 4;
    const int j = tid & 15;

    float mx = -INFINITY;
    for (int s = j; s < S; s += 16) mx = fmaxf(mx, sc[r][s]);
#pragma unroll
    for (int w = 1; w < 16; w <<= 1) mx = fmaxf(mx, __shfl_xor(mx, w));

    float sum = 0.f;
    for (int s = j; s < S; s += 16) {
        float e = __expf(sc[r][s] - mx);
        sc[r][s] = e;
        sum += e;
    }
#pragma unroll
    for (int w = 1; w < 16; w <<= 1) sum += __shfl_xor(sum, w);

    float invT = 1.0f / sum;
    float s2 = 0.f;
    for (int s = j; s < S; s += 16) {
        float v = sc[r][s] * invT;
        sc[r][s] = v;
        s2 += v;
    }
#pragma unroll
    for (int w = 1; w < 16; w <<= 1) s2 += __shfl_xor(s2, w);

    if (j == 0) {
        int mval = mask[b * L + l0 + r];
        facs[r] = mval ? 0.0f : 1.0f / (s2 + EPSF);
    }
    __syncthreads();

    float* arow = Aout + ((size_t)((b * H + h) * L + l0)) * S;
    for (int rr = 0; rr < 16; ++rr) {
        float f = facs[rr];
        for (int s = tid; s < S; s += 256)
            arow[(size_t)rr * S + s] = sc[rr][s] * f;
    }
}

// ---------------------------------------------------------------------------
// PV: Out[b,l,h*64+e] = sum_s A[b,h,l,s] * V[s, h*64+e]  (fp32-exact)
// ---------------------------------------------------------------------------
__global__ __launch_bounds__(256) void attn_pv(
    const float* __restrict__ Aout,  // [B*H*L, S]
    const float* __restrict__ Vp,    // [S, H*64]
    float* __restrict__ Out,         // [B*L, H*64]
    int B, int L, int S, int H) {
    __shared__ float At[64][33];
    __shared__ float Vt[32][65];

    const int blk = blockIdx.x;
    const int lt = blk & 3;
    const int h = (blk >> 2) & 15;
    const int b = blk >> 6;
    const int l0 = lt * 64;
    const int tid = threadIdx.x;
    const int tx = tid & 15;
    const int ty = tid >> 4;

    float acc[4][4] = {};
    const float* Abase = Aout + ((size_t)((b * H + h) * L + l0)) * S;

    for (int s0 = 0; s0 < S; s0 += 32) {
        int slen = S - s0;
#pragma unroll
        for (int i = 0; i < 8; ++i) {
            int idx = tid + i * 256;
            int rr = idx >> 5, cc = idx & 31;
            At[rr][cc] = (cc < slen) ? Abase[(size_t)rr * S + s0 + cc] : 0.0f;
        }
#pragma unroll
        for (int i = 0; i < 8; ++i) {
            int idx = tid + i * 256;
            int rr = idx >> 6, cc = idx & 63;
            Vt[rr][cc] = (rr < slen) ? Vp[(size_t)(s0 + rr) * 1024 + h * 64 + cc] : 0.0f;
        }
        __syncthreads();
#pragma unroll
        for (int kk = 0; kk < 32; ++kk) {
            float a[4], v[4];
#pragma unroll
            for (int i = 0; i < 4; ++i) a[i] = At[ty * 4 + i][kk];
#pragma unroll
            for (int jj = 0; jj < 4; ++jj) v[jj] = Vt[kk][tx * 4 + jj];
#pragma unroll
            for (int i = 0; i < 4; ++i)
#pragma unroll
                for (int jj = 0; jj < 4; ++jj) acc[i][jj] += a[i] * v[jj];
        }
        __syncthreads();
    }

#pragma unroll
    for (int i = 0; i < 4; ++i) {
        float* orow = Out + ((size_t)(b * L + l0 + ty * 4 + i)) * 1024 + h * 64;
#pragma unroll
        for (int jj = 0; jj < 4; ++jj) orow[tx * 4 + jj] = acc[i][jj];
    }
}

// ---------------------------------------------------------------------------
extern "C" void kernel_launch(void* const* d_in, const int* in_sizes, int n_in,
                              void* d_out, int out_size, void* d_ws, size_t ws_size,
                              hipStream_t stream) {
    const float* target = (const float*)d_in[0];  // [16,256,1024]
    const float* source = (const float*)d_in[1];  // [1000,4096]
    const float* value  = (const float*)d_in[2];  // [1000,4096]
    const int*   mask   = (const int*)d_in[3];    // [16,256]
    const float* Wq = (const float*)d_in[4];      // [1024,1024]
    const float* Wk = (const float*)d_in[5];      // [1024,4096]
    const float* bk = (const float*)d_in[6];      // [1024]
    const float* Wv = (const float*)d_in[7];      // [1024,4096]
    const float* bv = (const float*)d_in[8];      // [1024]
    const float* Wo = (const float*)d_in[9];      // [4096,1024]

    const int B = 16, L = 256, S = 1000, H = 16;
    const int dm = 1024, dllm = 4096, dk = 1024;
    const int BL = B * L;  // 4096

    // workspace: Qw + Kw + Vw + Ow fp32 = (4096+1000+1000+4096)*1024*4 B ~ 41.8 MB
    size_t need = ((size_t)BL * dk + (size_t)S * dk * 2 + (size_t)BL * dk) * sizeof(float);
    if (ws_size < need) return;  // refuse to corrupt memory; harness reports mismatch

    float* Qw = (float*)d_ws;                     // [4096,1024]
    float* Kw = Qw + (size_t)BL * dk;             // [1000,1024]
    float* Vw = Kw + (size_t)S * dk;              // [1000,1024]
    float* Ow = Vw + (size_t)S * dk;              // [4096,1024]
    float* outF = (float*)d_out;                  // [4096,4096]
    float* Aout = outF + (size_t)BL * dllm;       // [B*H*L, S]

    dim3 blk(256);

    // Q = target @ Wq^T
    gemm_nt_mfma<false><<<dim3(dk / 128, BL / 128), blk, 0, stream>>>(
        target, Wq, nullptr, Qw, BL, dk, dm);
    // K = source @ Wk^T + bk
    gemm_nt_mfma<true><<<dim3(dk / 128, (S + 127) / 128), blk, 0, stream>>>(
        source, Wk, bk, Kw, S, dk, dllm);
    // V = value @ Wv^T + bv
    gemm_nt_mfma<true><<<dim3(dk / 128, (S + 127) / 128), blk, 0, stream>>>(
        value, Wv, bv, Vw, S, dk, dllm);
    // scores + softmax + mask + renorm -> A
    attn_scores<<<dim3(B * H * (L / 16)), blk, 0, stream>>>(
        Qw, Kw, mask, Aout, B, L, S, H);
    // Out = A @ V
    attn_pv<<<dim3(B * H * (L / 64)), blk, 0, stream>>>(
        Aout, Vw, Ow, B, L, S, H);
    // final = Out @ Wo^T
    gemm_nt_mfma<false><<<dim3(dllm / 128, BL / 128), blk, 0, stream>>>(
        Ow, Wo, nullptr, outF, BL, dllm, dk);
}

// Round 4
// 1122.115 us; speedup vs baseline: 2.0559x; 2.0559x over previous
//
#include <hip/hip_runtime.h>

#define EPSF 1e-9f

typedef short bf16x8 __attribute__((ext_vector_type(8)));
typedef float f32x4 __attribute__((ext_vector_type(4)));

// round-to-nearest-even fp32 -> bf16 (bits)
__device__ inline unsigned short bf16_rne(float x) {
    unsigned u = __float_as_uint(x);
    return (unsigned short)((u + 0x7FFFu + ((u >> 16) & 1u)) >> 16);
}
__device__ inline float bf16_to_f(unsigned short h) {
    return __uint_as_float((unsigned)h << 16);
}

// ---------------------------------------------------------------------------
// MFMA GEMM: C[M,N] = A[M,K] * B[N,K]^T (+ bias[n]).  fp32 in/out.
// split-bf16 3-pass (Ah*Bh + Ah*Bl + Al*Bh), 128x128 tile, BK=32, 4 waves.
// ---------------------------------------------------------------------------
template <bool HAS_BIAS>
__global__ __launch_bounds__(256) void gemm_nt_mfma(const float* __restrict__ A,
                                                    const float* __restrict__ B,
                                                    const float* __restrict__ bias,
                                                    float* __restrict__ C,
                                                    int M, int N, int K) {
    __shared__ unsigned short Ah[128][32];
    __shared__ unsigned short Al[128][32];
    __shared__ unsigned short Bh[128][32];
    __shared__ unsigned short Bl[128][32];

    const int tid = threadIdx.x;
    const int lane = tid & 63;
    const int wave = tid >> 6;
    const int wr = wave >> 1;
    const int wc = wave & 1;
    const int brow = blockIdx.y * 128;
    const int bcol = blockIdx.x * 128;

    f32x4 acc[4][4] = {};

    const int lrow = tid >> 3;
    const int lcol = (tid & 7) * 4;

    float4 sa[4], sb[4];

#pragma unroll
    for (int it = 0; it < 4; ++it) {
        int row = it * 32 + lrow;
        int ar = min(brow + row, M - 1);
        float4 va = *(const float4*)(A + (size_t)ar * K + lcol);
        if (brow + row >= M) va = make_float4(0.f, 0.f, 0.f, 0.f);
        sa[it] = va;
        sb[it] = *(const float4*)(B + (size_t)(bcol + row) * K + lcol);
    }

    const int nt = K / 32;
    const int fr = lane & 15;
    const int fk = (lane >> 4) * 8;

    for (int t = 0; t < nt; ++t) {
        __syncthreads();
#pragma unroll
        for (int it = 0; it < 4; ++it) {
            int row = it * 32 + lrow;
            const float* pv = (const float*)&sa[it];
            const float* pw = (const float*)&sb[it];
#pragma unroll
            for (int q = 0; q < 4; ++q) {
                float x = pv[q];
                unsigned short h = bf16_rne(x);
                Ah[row][lcol + q] = h;
                Al[row][lcol + q] = bf16_rne(x - bf16_to_f(h));
            }
#pragma unroll
            for (int q = 0; q < 4; ++q) {
                float x = pw[q];
                unsigned short h = bf16_rne(x);
                Bh[row][lcol + q] = h;
                Bl[row][lcol + q] = bf16_rne(x - bf16_to_f(h));
            }
        }
        __syncthreads();
        if (t + 1 < nt) {
            int k0 = (t + 1) * 32;
#pragma unroll
            for (int it = 0; it < 4; ++it) {
                int row = it * 32 + lrow;
                int ar = min(brow + row, M - 1);
                float4 va = *(const float4*)(A + (size_t)ar * K + k0 + lcol);
                if (brow + row >= M) va = make_float4(0.f, 0.f, 0.f, 0.f);
                sa[it] = va;
                sb[it] = *(const float4*)(B + (size_t)(bcol + row) * K + k0 + lcol);
            }
        }
        bf16x8 fah[4], fal[4], fbh[4], fbl[4];
#pragma unroll
        for (int i = 0; i < 4; ++i) {
            int r = wr * 64 + i * 16 + fr;
            fah[i] = *(const bf16x8*)&Ah[r][fk];
            fal[i] = *(const bf16x8*)&Al[r][fk];
            int c = wc * 64 + i * 16 + fr;
            fbh[i] = *(const bf16x8*)&Bh[c][fk];
            fbl[i] = *(const bf16x8*)&Bl[c][fk];
        }
#pragma unroll
        for (int i = 0; i < 4; ++i)
#pragma unroll
            for (int j = 0; j < 4; ++j) {
                acc[i][j] = __builtin_amdgcn_mfma_f32_16x16x32_bf16(fal[i], fbh[j], acc[i][j], 0, 0, 0);
                acc[i][j] = __builtin_amdgcn_mfma_f32_16x16x32_bf16(fah[i], fbl[j], acc[i][j], 0, 0, 0);
                acc[i][j] = __builtin_amdgcn_mfma_f32_16x16x32_bf16(fah[i], fbh[j], acc[i][j], 0, 0, 0);
            }
    }

    const int fq = lane >> 4;
#pragma unroll
    for (int i = 0; i < 4; ++i) {
#pragma unroll
        for (int r = 0; r < 4; ++r) {
            int grow = brow + wr * 64 + i * 16 + fq * 4 + r;
            if (grow >= M) continue;
#pragma unroll
            for (int j = 0; j < 4; ++j) {
                int gcol = bcol + wc * 64 + j * 16 + fr;
                float v = acc[i][j][r];
                if (HAS_BIAS) v += bias[gcol];
                C[(size_t)grow * N + gcol] = v;
            }
        }
    }
}

// ---------------------------------------------------------------------------
// Fused attention: scores (split-bf16 MFMA) + exact softmax/mask/renorm +
// A-write + PV (split-bf16 MFMA).  One block = one (b,h); 8 waves x 32 q-rows.
// Two passes over S: pass1 online max/sum (no storage), pass2 recompute ->
// exp -> A -> PV with final stats.
// ---------------------------------------------------------------------------
__global__ __launch_bounds__(512) void attn_fused(
    const float* __restrict__ Q,    // [4096,1024] (b*256+l, h*64+d)
    const float* __restrict__ Kp,   // [1000,1024]
    const float* __restrict__ Vp,   // [1000,1024]
    const int* __restrict__ mask,   // [16,256]
    float* __restrict__ Aout,       // [(b*16+h)*256+l][1000]
    float* __restrict__ Ow) {       // [4096,1024]
    const int S = 1000, NT = 16;

    __shared__ __align__(16) char KhL[64 * 128];         // bf16 hi, row s (XOR swz)
    __shared__ __align__(16) char KlL[64 * 128];         // bf16 lo
    __shared__ __align__(16) unsigned short Vth[64][72]; // V^T hi, row e, pad 144B
    __shared__ __align__(16) unsigned short Vtl[64][72]; // V^T lo
    __shared__ __align__(16) char Pb[8 * 32 * 128];      // per-wave P (hi|lo planes)

    const int tid = threadIdx.x;
    const int lane = tid & 63;
    const int w = tid >> 6;
    const int le = lane & 15;
    const int quad = lane >> 4;
    const int bh = blockIdx.x;
    const int b = bh >> 4, h = bh & 15;

#define SWZ(row, byte) ((row) * 128 + ((byte) ^ (((row) & 7) << 4)))

    // ---- Q fragments in registers, scaled by 1/8 (exact), hi/lo split ----
    bf16x8 qh[2][2], ql[2][2];
#pragma unroll
    for (int m = 0; m < 2; ++m)
#pragma unroll
        for (int t = 0; t < 2; ++t) {
            const float* qp = Q + ((size_t)(b * 256 + w * 32 + m * 16 + le)) * 1024 + h * 64 + t * 32 + quad * 8;
            float4 x = *(const float4*)qp;
            float4 y = *(const float4*)(qp + 4);
            float v[8] = {x.x, x.y, x.z, x.w, y.x, y.y, y.z, y.w};
            bf16x8 hv, lv;
#pragma unroll
            for (int k = 0; k < 8; ++k) {
                float f = 0.125f * v[k];
                unsigned short hh = bf16_rne(f);
                hv[k] = (short)hh;
                lv[k] = (short)bf16_rne(f - bf16_to_f(hh));
            }
            qh[m][t] = hv;
            ql[m][t] = lv;
        }

    // ---- per-row mask values ----
    int mk[2][4];
#pragma unroll
    for (int m = 0; m < 2; ++m)
#pragma unroll
        for (int r = 0; r < 4; ++r)
            mk[m][r] = mask[b * 256 + w * 32 + m * 16 + quad * 4 + r];

    // ---- staging geometry ----
    const int sr = tid >> 3;       // tile row 0..63
    const int sc = tid & 7;        // 0..7
    float4 ka, kb;                 // K prefetch (8 floats)
    float vv[8];                   // V prefetch

#define LOADK(t)                                                              \
    {                                                                         \
        int s_ = min((t) * 64 + sr, S - 1);                                   \
        const float* p_ = Kp + (size_t)s_ * 1024 + h * 64 + sc * 8;           \
        ka = *(const float4*)p_;                                              \
        kb = *(const float4*)(p_ + 4);                                        \
    }
#define LOADV(t)                                                              \
    {                                                                         \
        int s_ = min((t) * 64 + sr, S - 1);                                   \
        const float* p_ = Vp + (size_t)s_ * 1024 + h * 64 + sc;               \
        _Pragma("unroll") for (int i_ = 0; i_ < 8; ++i_) vv[i_] = p_[8 * i_]; \
    }
#define STOREK()                                                              \
    {                                                                         \
        float v_[8] = {ka.x, ka.y, ka.z, ka.w, kb.x, kb.y, kb.z, kb.w};       \
        bf16x8 hv_, lv_;                                                      \
        _Pragma("unroll") for (int k_ = 0; k_ < 8; ++k_) {                    \
            unsigned short h_ = bf16_rne(v_[k_]);                             \
            hv_[k_] = (short)h_;                                              \
            lv_[k_] = (short)bf16_rne(v_[k_] - bf16_to_f(h_));                \
        }                                                                     \
        *(bf16x8*)(KhL + SWZ(sr, sc * 16)) = hv_;                             \
        *(bf16x8*)(KlL + SWZ(sr, sc * 16)) = lv_;                             \
    }
#define STOREV()                                                              \
    {                                                                         \
        _Pragma("unroll") for (int i_ = 0; i_ < 8; ++i_) {                    \
            unsigned short h_ = bf16_rne(vv[i_]);                             \
            Vth[sc + 8 * i_][sr] = h_;                                        \
            Vtl[sc + 8 * i_][sr] = bf16_rne(vv[i_] - bf16_to_f(h_));          \
        }                                                                     \
    }

    // scores for current LDS tile -> acc[2][4]
#define SCORES(acc)                                                           \
    _Pragma("unroll") for (int j = 0; j < 4; ++j) {                           \
        int srow_ = j * 16 + le;                                              \
        bf16x8 kh0 = *(const bf16x8*)(KhL + SWZ(srow_, quad * 16));           \
        bf16x8 kh1 = *(const bf16x8*)(KhL + SWZ(srow_, 64 + quad * 16));      \
        bf16x8 kl0 = *(const bf16x8*)(KlL + SWZ(srow_, quad * 16));           \
        bf16x8 kl1 = *(const bf16x8*)(KlL + SWZ(srow_, 64 + quad * 16));      \
        _Pragma("unroll") for (int m = 0; m < 2; ++m) {                       \
            acc[m][j] = __builtin_amdgcn_mfma_f32_16x16x32_bf16(ql[m][0], kh0, acc[m][j], 0, 0, 0); \
            acc[m][j] = __builtin_amdgcn_mfma_f32_16x16x32_bf16(qh[m][0], kl0, acc[m][j], 0, 0, 0); \
            acc[m][j] = __builtin_amdgcn_mfma_f32_16x16x32_bf16(qh[m][0], kh0, acc[m][j], 0, 0, 0); \
            acc[m][j] = __builtin_amdgcn_mfma_f32_16x16x32_bf16(ql[m][1], kh1, acc[m][j], 0, 0, 0); \
            acc[m][j] = __builtin_amdgcn_mfma_f32_16x16x32_bf16(qh[m][1], kl1, acc[m][j], 0, 0, 0); \
            acc[m][j] = __builtin_amdgcn_mfma_f32_16x16x32_bf16(qh[m][1], kh1, acc[m][j], 0, 0, 0); \
        }                                                                     \
    }

    // ================= pass 1: online max / sum =================
    float mrun[2][4], lrun[2][4];
#pragma unroll
    for (int m = 0; m < 2; ++m)
#pragma unroll
        for (int r = 0; r < 4; ++r) { mrun[m][r] = -1e30f; lrun[m][r] = 0.f; }

    LOADK(0);
    for (int t = 0; t < NT; ++t) {
        __syncthreads();
        STOREK();
        __syncthreads();
        if (t + 1 < NT) LOADK(t + 1);

        f32x4 acc[2][4] = {};
        SCORES(acc);

        if (t == NT - 1) {
#pragma unroll
            for (int m = 0; m < 2; ++m)
#pragma unroll
                for (int j = 0; j < 4; ++j)
                    if (j * 16 + le >= 40) {
#pragma unroll
                        for (int r = 0; r < 4; ++r) acc[m][j][r] = -1e30f;
                    }
        }

        float tm[2][4];
#pragma unroll
        for (int m = 0; m < 2; ++m)
#pragma unroll
            for (int r = 0; r < 4; ++r)
                tm[m][r] = fmaxf(fmaxf(acc[m][0][r], acc[m][1][r]),
                                 fmaxf(acc[m][2][r], acc[m][3][r]));
#pragma unroll
        for (int xm = 1; xm < 16; xm <<= 1)
#pragma unroll
            for (int m = 0; m < 2; ++m)
#pragma unroll
                for (int r = 0; r < 4; ++r)
                    tm[m][r] = fmaxf(tm[m][r], __shfl_xor(tm[m][r], xm));

        float mn[2][4], ts[2][4];
#pragma unroll
        for (int m = 0; m < 2; ++m)
#pragma unroll
            for (int r = 0; r < 4; ++r) {
                mn[m][r] = fmaxf(mrun[m][r], tm[m][r]);
                float s = 0.f;
#pragma unroll
                for (int j = 0; j < 4; ++j) s += __expf(acc[m][j][r] - mn[m][r]);
                ts[m][r] = s;
            }
#pragma unroll
        for (int xm = 1; xm < 16; xm <<= 1)
#pragma unroll
            for (int m = 0; m < 2; ++m)
#pragma unroll
                for (int r = 0; r < 4; ++r)
                    ts[m][r] += __shfl_xor(ts[m][r], xm);
#pragma unroll
        for (int m = 0; m < 2; ++m)
#pragma unroll
            for (int r = 0; r < 4; ++r) {
                lrun[m][r] = lrun[m][r] * __expf(mrun[m][r] - mn[m][r]) + ts[m][r];
                mrun[m][r] = mn[m][r];
            }
    }

    // fac = invT * 1/(s2+eps);  s2 = l*invT (~1).  masked rows -> 0.
    float fac[2][4];
#pragma unroll
    for (int m = 0; m < 2; ++m)
#pragma unroll
        for (int r = 0; r < 4; ++r) {
            float inv = 1.0f / lrun[m][r];
            float s2 = lrun[m][r] * inv;
            fac[m][r] = mk[m][r] ? 0.0f : inv / (s2 + EPSF);
        }

    // ================= pass 2: recompute -> A, PV =================
    f32x4 o[2][4] = {};
    char* pb = Pb + w * 32 * 128;

    LOADK(0);
    LOADV(0);
    for (int t = 0; t < NT; ++t) {
        __syncthreads();
        STOREK();
        STOREV();
        __syncthreads();
        if (t + 1 < NT) { LOADK(t + 1); LOADV(t + 1); }

        f32x4 acc[2][4] = {};
        SCORES(acc);

        // e = exp(score - m_fin); padded cols -> 0
        const bool last = (t == NT - 1);
#pragma unroll
        for (int m = 0; m < 2; ++m)
#pragma unroll
            for (int j = 0; j < 4; ++j) {
                bool valid = !last || (j * 16 + le < 40);
#pragma unroll
                for (int r = 0; r < 4; ++r)
                    acc[m][j][r] = valid ? __expf(acc[m][j][r] - mrun[m][r]) : 0.f;
            }

        // ---- write A ----
#pragma unroll
        for (int m = 0; m < 2; ++m)
#pragma unroll
            for (int r = 0; r < 4; ++r) {
                float f = fac[m][r];
                size_t ro = ((size_t)bh * 256 + w * 32 + m * 16 + quad * 4 + r) * 1000 + t * 64;
#pragma unroll
                for (int j = 0; j < 4; ++j) {
                    int sl = j * 16 + le;
                    if (!last || sl < 40) Aout[ro + sl] = acc[m][j][r] * f;
                }
            }

        // ---- PV: stage P (wave-private), split-bf16 MFMA ----
#pragma unroll
        for (int ks = 0; ks < 2; ++ks) {
#pragma unroll
            for (int m = 0; m < 2; ++m)
#pragma unroll
                for (int jj = 0; jj < 2; ++jj) {
                    int j = ks * 2 + jj;
#pragma unroll
                    for (int r = 0; r < 4; ++r) {
                        float e = acc[m][j][r];
                        unsigned short hh = bf16_rne(e);
                        unsigned short llo = bf16_rne(e - bf16_to_f(hh));
                        int q = m * 16 + quad * 4 + r;
                        int sb = (jj * 16 + le) * 2;
                        *(unsigned short*)(pb + SWZ(q, sb)) = hh;
                        *(unsigned short*)(pb + SWZ(q, 64 + sb)) = llo;
                    }
                }
            bf16x8 ph[2], pl[2];
#pragma unroll
            for (int m = 0; m < 2; ++m) {
                ph[m] = *(const bf16x8*)(pb + SWZ(m * 16 + le, quad * 16));
                pl[m] = *(const bf16x8*)(pb + SWZ(m * 16 + le, 64 + quad * 16));
            }
#pragma unroll
            for (int n = 0; n < 4; ++n) {
                const char* vb = (const char*)Vth + (n * 16 + le) * 144 + ks * 64 + quad * 16;
                const char* vc = (const char*)Vtl + (n * 16 + le) * 144 + ks * 64 + quad * 16;
                bf16x8 vh = *(const bf16x8*)vb;
                bf16x8 vl = *(const bf16x8*)vc;
#pragma unroll
                for (int m = 0; m < 2; ++m) {
                    o[m][n] = __builtin_amdgcn_mfma_f32_16x16x32_bf16(pl[m], vh, o[m][n], 0, 0, 0);
                    o[m][n] = __builtin_amdgcn_mfma_f32_16x16x32_bf16(ph[m], vl, o[m][n], 0, 0, 0);
                    o[m][n] = __builtin_amdgcn_mfma_f32_16x16x32_bf16(ph[m], vh, o[m][n], 0, 0, 0);
                }
            }
        }
    }

    // ---- final O store ----
#pragma unroll
    for (int m = 0; m < 2; ++m)
#pragma unroll
        for (int r = 0; r < 4; ++r) {
            float f = fac[m][r];
            size_t ro = (size_t)(b * 256 + w * 32 + m * 16 + quad * 4 + r) * 1024 + h * 64;
#pragma unroll
            for (int n = 0; n < 4; ++n)
                Ow[ro + n * 16 + le] = o[m][n][r] * f;
        }
#undef SWZ
#undef LOADK
#undef LOADV
#undef STOREK
#undef STOREV
#undef SCORES
}

// ---------------------------------------------------------------------------
extern "C" void kernel_launch(void* const* d_in, const int* in_sizes, int n_in,
                              void* d_out, int out_size, void* d_ws, size_t ws_size,
                              hipStream_t stream) {
    const float* target = (const float*)d_in[0];  // [16,256,1024]
    const float* source = (const float*)d_in[1];  // [1000,4096]
    const float* value  = (const float*)d_in[2];  // [1000,4096]
    const int*   mask   = (const int*)d_in[3];    // [16,256]
    const float* Wq = (const float*)d_in[4];      // [1024,1024]
    const float* Wk = (const float*)d_in[5];      // [1024,4096]
    const float* bk = (const float*)d_in[6];      // [1024]
    const float* Wv = (const float*)d_in[7];      // [1024,4096]
    const float* bv = (const float*)d_in[8];      // [1024]
    const float* Wo = (const float*)d_in[9];      // [4096,1024]

    const int B = 16, L = 256, S = 1000, H = 16;
    const int dm = 1024, dllm = 4096, dk = 1024;
    const int BL = B * L;  // 4096

    size_t need = ((size_t)BL * dk + (size_t)S * dk * 2 + (size_t)BL * dk) * sizeof(float);
    if (ws_size < need) return;

    float* Qw = (float*)d_ws;                     // [4096,1024]
    float* Kw = Qw + (size_t)BL * dk;             // [1000,1024]
    float* Vw = Kw + (size_t)S * dk;              // [1000,1024]
    float* Ow = Vw + (size_t)S * dk;              // [4096,1024]
    float* outF = (float*)d_out;                  // [4096,4096]
    float* Aout = outF + (size_t)BL * dllm;       // [B*H*L, S]

    dim3 blk(256);

    gemm_nt_mfma<false><<<dim3(dk / 128, BL / 128), blk, 0, stream>>>(
        target, Wq, nullptr, Qw, BL, dk, dm);
    gemm_nt_mfma<true><<<dim3(dk / 128, (S + 127) / 128), blk, 0, stream>>>(
        source, Wk, bk, Kw, S, dk, dllm);
    gemm_nt_mfma<true><<<dim3(dk / 128, (S + 127) / 128), blk, 0, stream>>>(
        value, Wv, bv, Vw, S, dk, dllm);

    attn_fused<<<dim3(B * H), dim3(512), 0, stream>>>(
        Qw, Kw, Vw, mask, Aout, Ow);

    gemm_nt_mfma<false><<<dim3(dllm / 128, BL / 128), blk, 0, stream>>>(
        Ow, Wo, nullptr, outF, BL, dllm, dk);
}

// Round 5
// 800.080 us; speedup vs baseline: 2.8834x; 1.4025x over previous
//
#include <hip/hip_runtime.h>

#define EPSF 1e-9f

typedef _Float16 half8 __attribute__((ext_vector_type(8)));
typedef float f32x4 __attribute__((ext_vector_type(4)));

// ---------------------------------------------------------------------------
// Pre-pass: split fp32 -> fp16 hi/lo planes.  x ~= hi + lo, |err| ~ 2^-21 |x|.
// n8 = n/8 (all our matrices are divisible by 8).
// ---------------------------------------------------------------------------
__global__ __launch_bounds__(256) void split_planes(const float* __restrict__ in,
                                                    _Float16* __restrict__ hp,
                                                    _Float16* __restrict__ lp,
                                                    int n8) {
    int i = blockIdx.x * 256 + threadIdx.x;
    if (i >= n8) return;
    const float4* p = (const float4*)in + (size_t)i * 2;
    float4 a = p[0], b = p[1];
    float v[8] = {a.x, a.y, a.z, a.w, b.x, b.y, b.z, b.w};
    half8 hv, lv;
#pragma unroll
    for (int k = 0; k < 8; ++k) {
        _Float16 h = (_Float16)v[k];
        hv[k] = h;
        lv[k] = (_Float16)(v[k] - (float)h);
    }
    ((half8*)hp)[i] = hv;
    ((half8*)lp)[i] = lv;
}

// ---------------------------------------------------------------------------
// NT GEMM on fp16 hi/lo planes: C[M,N] = (Ah+Al)(Bh+Bl)^T (+bias), 3-pass
// (Al*Bh + Ah*Bl + Ah*Bh), mfma_f32_16x16x32_f16.
// BM=64, BN=128, BK=32, 256 thr = 4 waves (2m x 2n), 32x64 per wave.
// B_F32: B given as fp32, converted during staging (used for Wo only).
// OUT_PLANES: write C as fp16 hi/lo planes; else fp32.
// blockIdx.z selects input/output set via zs* strides (K/V fusion).
// ---------------------------------------------------------------------------
template <bool HAS_BIAS, bool B_F32, bool OUT_PLANES>
__global__ __launch_bounds__(256, 4) void gemm_f16(
    const _Float16* __restrict__ Ahp, const _Float16* __restrict__ Alp,
    const _Float16* __restrict__ Bhp, const _Float16* __restrict__ Blp,
    const float* __restrict__ Bf,
    const float* __restrict__ bias0, const float* __restrict__ bias1,
    float* __restrict__ Cf,
    _Float16* __restrict__ Chp, _Float16* __restrict__ Clp,
    int M, int N, int K, size_t zsA, size_t zsB, size_t zsC) {
    const int z = blockIdx.z;
    Ahp += z * zsA; Alp += z * zsA;
    if (!B_F32) { Bhp += z * zsB; Blp += z * zsB; }
    else        { Bf  += z * zsB; }
    if (OUT_PLANES) { Chp += z * zsC; Clp += z * zsC; }
    const float* bias = (HAS_BIAS && z) ? bias1 : bias0;

    __shared__ __align__(16) char lds[24576];
    const int AsHo = 0, AsLo = 4096, BsHo = 8192, BsLo = 16384;

    const int tid = threadIdx.x;
    const int lane = tid & 63;
    const int w = tid >> 6;
    const int wm = w >> 1, wn = w & 1;
    const int fr = lane & 15, quad = lane >> 4;
    const int bm = blockIdx.y * 64;
    const int bn = blockIdx.x * 128;

    const int srow = tid >> 2;   // 0..63
    const int sslot = tid & 3;   // 16B slot within 64B row

    f32x4 acc[2][4] = {};
    half8 sAh, sAl, sBh[2], sBl[2];

#define GLOAD(k0)                                                             \
    {                                                                         \
        int gr = min(bm + srow, M - 1);                                       \
        size_t ao = (size_t)gr * K + (k0) + sslot * 8;                        \
        sAh = *(const half8*)(Ahp + ao);                                      \
        sAl = *(const half8*)(Alp + ao);                                      \
        _Pragma("unroll") for (int it = 0; it < 2; ++it) {                    \
            size_t bo = (size_t)(bn + it * 64 + srow) * K + (k0) + sslot * 8; \
            if (B_F32) {                                                      \
                float4 f0 = *(const float4*)(Bf + bo);                        \
                float4 f1 = *(const float4*)(Bf + bo + 4);                    \
                float vv[8] = {f0.x, f0.y, f0.z, f0.w, f1.x, f1.y, f1.z, f1.w}; \
                half8 hv, lv;                                                 \
                _Pragma("unroll") for (int q = 0; q < 8; ++q) {               \
                    _Float16 hh = (_Float16)vv[q];                            \
                    hv[q] = hh;                                               \
                    lv[q] = (_Float16)(vv[q] - (float)hh);                    \
                }                                                             \
                sBh[it] = hv; sBl[it] = lv;                                   \
            } else {                                                          \
                sBh[it] = *(const half8*)(Bhp + bo);                          \
                sBl[it] = *(const half8*)(Blp + bo);                          \
            }                                                                 \
        }                                                                     \
    }

    GLOAD(0);
    const int nt = K / 32;

    for (int t = 0; t < nt; ++t) {
        __syncthreads();
        *(half8*)(lds + AsHo + srow * 64 + sslot * 16) = sAh;
        *(half8*)(lds + AsLo + srow * 64 + sslot * 16) = sAl;
#pragma unroll
        for (int it = 0; it < 2; ++it) {
            int r = it * 64 + srow;
            *(half8*)(lds + BsHo + r * 64 + sslot * 16) = sBh[it];
            *(half8*)(lds + BsLo + r * 64 + sslot * 16) = sBl[it];
        }
        __syncthreads();
        if (t + 1 < nt) GLOAD((t + 1) * 32);

        half8 fah[2], fal[2], fbh[4], fbl[4];
#pragma unroll
        for (int m = 0; m < 2; ++m) {
            int off = (wm * 32 + m * 16 + fr) * 64 + quad * 16;
            fah[m] = *(const half8*)(lds + AsHo + off);
            fal[m] = *(const half8*)(lds + AsLo + off);
        }
#pragma unroll
        for (int n = 0; n < 4; ++n) {
            int off = (wn * 64 + n * 16 + fr) * 64 + quad * 16;
            fbh[n] = *(const half8*)(lds + BsHo + off);
            fbl[n] = *(const half8*)(lds + BsLo + off);
        }
#pragma unroll
        for (int m = 0; m < 2; ++m)
#pragma unroll
            for (int n = 0; n < 4; ++n) {
                acc[m][n] = __builtin_amdgcn_mfma_f32_16x16x32_f16(fal[m], fbh[n], acc[m][n], 0, 0, 0);
                acc[m][n] = __builtin_amdgcn_mfma_f32_16x16x32_f16(fah[m], fbl[n], acc[m][n], 0, 0, 0);
                acc[m][n] = __builtin_amdgcn_mfma_f32_16x16x32_f16(fah[m], fbh[n], acc[m][n], 0, 0, 0);
            }
    }
#undef GLOAD

    // C/D layout: col = lane&15, row = (lane>>4)*4 + reg  (m89/m91, HW-verified)
#pragma unroll
    for (int m = 0; m < 2; ++m)
#pragma unroll
        for (int r = 0; r < 4; ++r) {
            int grow = bm + wm * 32 + m * 16 + quad * 4 + r;
            if (grow >= M) continue;
#pragma unroll
            for (int n = 0; n < 4; ++n) {
                int gcol = bn + wn * 64 + n * 16 + fr;
                float v = acc[m][n][r];
                if (HAS_BIAS) v += bias[gcol];
                if (OUT_PLANES) {
                    _Float16 hh = (_Float16)v;
                    Chp[(size_t)grow * N + gcol] = hh;
                    Clp[(size_t)grow * N + gcol] = (_Float16)(v - (float)hh);
                } else {
                    Cf[(size_t)grow * N + gcol] = v;
                }
            }
        }
}

// ---------------------------------------------------------------------------
// Fused attention on fp16 planes.  One block = one (b,h); 8 waves x 32 q-rows.
// Pass1: online max/sum.  Pass2: recompute -> exp -> A-write -> PV.
// Scale 1/8 applied to fp32 scores post-MFMA (exact semantics).
// Outputs: A (fp32, harness output) and Ow as fp16 hi/lo planes.
// ---------------------------------------------------------------------------
__global__ __launch_bounds__(512) void attn_fused(
    const _Float16* __restrict__ Qh, const _Float16* __restrict__ Ql,
    const _Float16* __restrict__ Kh, const _Float16* __restrict__ Kl,
    const _Float16* __restrict__ Vh, const _Float16* __restrict__ Vl,
    const int* __restrict__ mask,
    float* __restrict__ Aout,
    _Float16* __restrict__ Owh, _Float16* __restrict__ Owl) {
    const int S = 1000, NT = 16;

    __shared__ __align__(16) char KhL[64 * 128];
    __shared__ __align__(16) char KlL[64 * 128];
    __shared__ __align__(16) _Float16 Vth[64][72];
    __shared__ __align__(16) _Float16 Vtl[64][72];
    __shared__ __align__(16) char Pb[8 * 32 * 128];

    const int tid = threadIdx.x;
    const int lane = tid & 63;
    const int w = tid >> 6;
    const int le = lane & 15;
    const int quad = lane >> 4;
    const int bh = blockIdx.x;
    const int b = bh >> 4, h = bh & 15;

#define SWZ(row, byte) ((row) * 128 + ((byte) ^ (((row) & 7) << 4)))

    // ---- Q fragments straight from planes ----
    half8 qh[2][2], ql[2][2];
#pragma unroll
    for (int m = 0; m < 2; ++m)
#pragma unroll
        for (int t = 0; t < 2; ++t) {
            size_t qo = ((size_t)(b * 256 + w * 32 + m * 16 + le)) * 1024 + h * 64 + t * 32 + quad * 8;
            qh[m][t] = *(const half8*)(Qh + qo);
            ql[m][t] = *(const half8*)(Ql + qo);
        }

    int mk[2][4];
#pragma unroll
    for (int m = 0; m < 2; ++m)
#pragma unroll
        for (int r = 0; r < 4; ++r)
            mk[m][r] = mask[b * 256 + w * 32 + m * 16 + quad * 4 + r];

    const int sr = tid >> 3;  // 0..63
    const int sc = tid & 7;   // 0..7
    half8 kha, kla;
    _Float16 vvh[8], vvl[8];

#define LOADK(t)                                                       \
    {                                                                  \
        int s_ = min((t) * 64 + sr, S - 1);                            \
        size_t o_ = (size_t)s_ * 1024 + h * 64 + sc * 8;               \
        kha = *(const half8*)(Kh + o_);                                \
        kla = *(const half8*)(Kl + o_);                                \
    }
#define LOADV(t)                                                       \
    {                                                                  \
        int s_ = min((t) * 64 + sr, S - 1);                            \
        size_t o_ = (size_t)s_ * 1024 + h * 64 + sc;                   \
        _Pragma("unroll") for (int i_ = 0; i_ < 8; ++i_) {             \
            vvh[i_] = Vh[o_ + 8 * i_];                                 \
            vvl[i_] = Vl[o_ + 8 * i_];                                 \
        }                                                              \
    }
#define STOREK()                                                       \
    {                                                                  \
        *(half8*)(KhL + SWZ(sr, sc * 16)) = kha;                       \
        *(half8*)(KlL + SWZ(sr, sc * 16)) = kla;                       \
    }
#define STOREV()                                                       \
    {                                                                  \
        _Pragma("unroll") for (int i_ = 0; i_ < 8; ++i_) {             \
            Vth[sc + 8 * i_][sr] = vvh[i_];                            \
            Vtl[sc + 8 * i_][sr] = vvl[i_];                            \
        }                                                              \
    }
#define SCORES(acc)                                                           \
    _Pragma("unroll") for (int j = 0; j < 4; ++j) {                           \
        int srow_ = j * 16 + le;                                              \
        half8 kh0 = *(const half8*)(KhL + SWZ(srow_, quad * 16));             \
        half8 kh1 = *(const half8*)(KhL + SWZ(srow_, 64 + quad * 16));        \
        half8 kl0 = *(const half8*)(KlL + SWZ(srow_, quad * 16));             \
        half8 kl1 = *(const half8*)(KlL + SWZ(srow_, 64 + quad * 16));        \
        _Pragma("unroll") for (int m = 0; m < 2; ++m) {                       \
            acc[m][j] = __builtin_amdgcn_mfma_f32_16x16x32_f16(ql[m][0], kh0, acc[m][j], 0, 0, 0); \
            acc[m][j] = __builtin_amdgcn_mfma_f32_16x16x32_f16(qh[m][0], kl0, acc[m][j], 0, 0, 0); \
            acc[m][j] = __builtin_amdgcn_mfma_f32_16x16x32_f16(qh[m][0], kh0, acc[m][j], 0, 0, 0); \
            acc[m][j] = __builtin_amdgcn_mfma_f32_16x16x32_f16(ql[m][1], kh1, acc[m][j], 0, 0, 0); \
            acc[m][j] = __builtin_amdgcn_mfma_f32_16x16x32_f16(qh[m][1], kl1, acc[m][j], 0, 0, 0); \
            acc[m][j] = __builtin_amdgcn_mfma_f32_16x16x32_f16(qh[m][1], kh1, acc[m][j], 0, 0, 0); \
        }                                                                     \
    }
#define SCALEACC(acc)                                                  \
    _Pragma("unroll") for (int m = 0; m < 2; ++m)                      \
        _Pragma("unroll") for (int j = 0; j < 4; ++j) acc[m][j] *= 0.125f;

    // ================= pass 1 =================
    float mrun[2][4], lrun[2][4];
#pragma unroll
    for (int m = 0; m < 2; ++m)
#pragma unroll
        for (int r = 0; r < 4; ++r) { mrun[m][r] = -1e30f; lrun[m][r] = 0.f; }

    LOADK(0);
    for (int t = 0; t < NT; ++t) {
        __syncthreads();
        STOREK();
        __syncthreads();
        if (t + 1 < NT) LOADK(t + 1);

        f32x4 acc[2][4] = {};
        SCORES(acc);
        SCALEACC(acc);

        if (t == NT - 1) {
#pragma unroll
            for (int m = 0; m < 2; ++m)
#pragma unroll
                for (int j = 0; j < 4; ++j)
                    if (j * 16 + le >= 40) {
#pragma unroll
                        for (int r = 0; r < 4; ++r) acc[m][j][r] = -1e30f;
                    }
        }

        float tm[2][4];
#pragma unroll
        for (int m = 0; m < 2; ++m)
#pragma unroll
            for (int r = 0; r < 4; ++r)
                tm[m][r] = fmaxf(fmaxf(acc[m][0][r], acc[m][1][r]),
                                 fmaxf(acc[m][2][r], acc[m][3][r]));
#pragma unroll
        for (int xm = 1; xm < 16; xm <<= 1)
#pragma unroll
            for (int m = 0; m < 2; ++m)
#pragma unroll
                for (int r = 0; r < 4; ++r)
                    tm[m][r] = fmaxf(tm[m][r], __shfl_xor(tm[m][r], xm));

        float mn[2][4], ts[2][4];
#pragma unroll
        for (int m = 0; m < 2; ++m)
#pragma unroll
            for (int r = 0; r < 4; ++r) {
                mn[m][r] = fmaxf(mrun[m][r], tm[m][r]);
                float s = 0.f;
#pragma unroll
                for (int j = 0; j < 4; ++j) s += __expf(acc[m][j][r] - mn[m][r]);
                ts[m][r] = s;
            }
#pragma unroll
        for (int xm = 1; xm < 16; xm <<= 1)
#pragma unroll
            for (int m = 0; m < 2; ++m)
#pragma unroll
                for (int r = 0; r < 4; ++r)
                    ts[m][r] += __shfl_xor(ts[m][r], xm);
#pragma unroll
        for (int m = 0; m < 2; ++m)
#pragma unroll
            for (int r = 0; r < 4; ++r) {
                lrun[m][r] = lrun[m][r] * __expf(mrun[m][r] - mn[m][r]) + ts[m][r];
                mrun[m][r] = mn[m][r];
            }
    }

    float fac[2][4];
#pragma unroll
    for (int m = 0; m < 2; ++m)
#pragma unroll
        for (int r = 0; r < 4; ++r) {
            float inv = 1.0f / lrun[m][r];
            float s2 = lrun[m][r] * inv;
            fac[m][r] = mk[m][r] ? 0.0f : inv / (s2 + EPSF);
        }

    // ================= pass 2 =================
    f32x4 o[2][4] = {};
    char* pb = Pb + w * 32 * 128;

    LOADK(0);
    LOADV(0);
    for (int t = 0; t < NT; ++t) {
        __syncthreads();
        STOREK();
        STOREV();
        __syncthreads();
        if (t + 1 < NT) { LOADK(t + 1); LOADV(t + 1); }

        f32x4 acc[2][4] = {};
        SCORES(acc);
        SCALEACC(acc);

        const bool last = (t == NT - 1);
#pragma unroll
        for (int m = 0; m < 2; ++m)
#pragma unroll
            for (int j = 0; j < 4; ++j) {
                bool valid = !last || (j * 16 + le < 40);
#pragma unroll
                for (int r = 0; r < 4; ++r)
                    acc[m][j][r] = valid ? __expf(acc[m][j][r] - mrun[m][r]) : 0.f;
            }

        // ---- write A ----
#pragma unroll
        for (int m = 0; m < 2; ++m)
#pragma unroll
            for (int r = 0; r < 4; ++r) {
                float f = fac[m][r];
                size_t ro = ((size_t)bh * 256 + w * 32 + m * 16 + quad * 4 + r) * 1000 + t * 64;
#pragma unroll
                for (int j = 0; j < 4; ++j) {
                    int sl = j * 16 + le;
                    if (!last || sl < 40) Aout[ro + sl] = acc[m][j][r] * f;
                }
            }

        // ---- PV ----
#pragma unroll
        for (int ks = 0; ks < 2; ++ks) {
#pragma unroll
            for (int m = 0; m < 2; ++m)
#pragma unroll
                for (int jj = 0; jj < 2; ++jj) {
                    int j = ks * 2 + jj;
#pragma unroll
                    for (int r = 0; r < 4; ++r) {
                        float e = acc[m][j][r];
                        _Float16 hh = (_Float16)e;
                        _Float16 llo = (_Float16)(e - (float)hh);
                        int q = m * 16 + quad * 4 + r;
                        int sb = (jj * 16 + le) * 2;
                        *(_Float16*)(pb + SWZ(q, sb)) = hh;
                        *(_Float16*)(pb + SWZ(q, 64 + sb)) = llo;
                    }
                }
            half8 ph[2], pl[2];
#pragma unroll
            for (int m = 0; m < 2; ++m) {
                ph[m] = *(const half8*)(pb + SWZ(m * 16 + le, quad * 16));
                pl[m] = *(const half8*)(pb + SWZ(m * 16 + le, 64 + quad * 16));
            }
#pragma unroll
            for (int n = 0; n < 4; ++n) {
                const char* vb = (const char*)Vth + (n * 16 + le) * 144 + ks * 64 + quad * 16;
                const char* vc = (const char*)Vtl + (n * 16 + le) * 144 + ks * 64 + quad * 16;
                half8 vh = *(const half8*)vb;
                half8 vl = *(const half8*)vc;
#pragma unroll
                for (int m = 0; m < 2; ++m) {
                    o[m][n] = __builtin_amdgcn_mfma_f32_16x16x32_f16(pl[m], vh, o[m][n], 0, 0, 0);
                    o[m][n] = __builtin_amdgcn_mfma_f32_16x16x32_f16(ph[m], vl, o[m][n], 0, 0, 0);
                    o[m][n] = __builtin_amdgcn_mfma_f32_16x16x32_f16(ph[m], vh, o[m][n], 0, 0, 0);
                }
            }
        }
    }

    // ---- Ow as fp16 planes ----
#pragma unroll
    for (int m = 0; m < 2; ++m)
#pragma unroll
        for (int r = 0; r < 4; ++r) {
            float f = fac[m][r];
            size_t ro = (size_t)(b * 256 + w * 32 + m * 16 + quad * 4 + r) * 1024 + h * 64;
#pragma unroll
            for (int n = 0; n < 4; ++n) {
                float v = o[m][n][r] * f;
                _Float16 hh = (_Float16)v;
                Owh[ro + n * 16 + le] = hh;
                Owl[ro + n * 16 + le] = (_Float16)(v - (float)hh);
            }
        }
#undef SWZ
#undef LOADK
#undef LOADV
#undef STOREK
#undef STOREV
#undef SCORES
#undef SCALEACC
}

// ---------------------------------------------------------------------------
extern "C" void kernel_launch(void* const* d_in, const int* in_sizes, int n_in,
                              void* d_out, int out_size, void* d_ws, size_t ws_size,
                              hipStream_t stream) {
    const float* target = (const float*)d_in[0];  // [16,256,1024]
    const float* source = (const float*)d_in[1];  // [1000,4096]
    const float* value  = (const float*)d_in[2];  // [1000,4096]
    const int*   mask   = (const int*)d_in[3];    // [16,256]
    const float* Wq = (const float*)d_in[4];      // [1024,1024]
    const float* Wk = (const float*)d_in[5];      // [1024,4096]
    const float* bk = (const float*)d_in[6];
    const float* Wv = (const float*)d_in[7];      // [1024,4096]
    const float* bv = (const float*)d_in[8];
    const float* Wo = (const float*)d_in[9];      // [4096,1024]

    const int B = 16, L = 256, S = 1000, H = 16;
    const int dm = 1024, dllm = 4096, dk = 1024;
    const int BL = B * L;  // 4096

    // ---- ws: fp16 hi/lo planes for Q/K/V/Ow (41.75 MB) ----
    size_t need = (size_t)20873216 * sizeof(_Float16);
    if (ws_size < need) return;
    _Float16* wsf = (_Float16*)d_ws;
    _Float16* QwH = wsf;                 // 4,194,304
    _Float16* QwL = QwH + 4194304;
    _Float16* KwH = QwL + 4194304;       // 1,024,000
    _Float16* VwH = KwH + 1024000;       // 1,024,000  (contiguous with KwH)
    _Float16* KwL = VwH + 1024000;
    _Float16* VwL = KwL + 1024000;
    _Float16* OwH = VwL + 1024000;       // 4,194,304
    _Float16* OwL = OwH + 4194304;

    float* outF = (float*)d_out;                  // [4096,4096]
    float* Aout = outF + (size_t)BL * dllm;       // [B*H*L, S] = 262 MB

    // ---- prepass planes live in the (not-yet-written) Aout region ----
    _Float16* scr = (_Float16*)Aout;
    _Float16* tgtH = scr;                // 4,194,304
    _Float16* tgtL = tgtH + 4194304;
    _Float16* srcH = tgtL + 4194304;     // 4,096,000
    _Float16* srcL = srcH + 4096000;
    _Float16* valH = srcL + 4096000;     // 4,096,000
    _Float16* valL = valH + 4096000;
    _Float16* wqH  = valL + 4096000;     // 1,048,576
    _Float16* wqL  = wqH + 1048576;
    _Float16* wkH  = wqL + 1048576;      // 4,194,304
    _Float16* wkL  = wkH + 4194304;
    _Float16* wvH  = wkL + 4194304;      // 4,194,304
    _Float16* wvL  = wvH + 4194304;

    dim3 blk(256);
#define SPLIT(src_, h_, l_, n_) \
    split_planes<<<dim3(((n_) / 8 + 255) / 256), blk, 0, stream>>>(src_, h_, l_, (n_) / 8)
    SPLIT(target, tgtH, tgtL, 4194304);
    SPLIT(source, srcH, srcL, 4096000);
    SPLIT(value,  valH, valL, 4096000);
    SPLIT(Wq,     wqH,  wqL,  1048576);
    SPLIT(Wk,     wkH,  wkL,  4194304);
    SPLIT(Wv,     wvH,  wvL,  4194304);
#undef SPLIT

    // Q = target @ Wq^T   -> Qw planes.  grid 8 x 64 = 512
    gemm_f16<false, false, true><<<dim3(dk / 128, BL / 64), blk, 0, stream>>>(
        tgtH, tgtL, wqH, wqL, nullptr, nullptr, nullptr,
        nullptr, QwH, QwL, BL, dk, dm, 0, 0, 0);

    // K/V = {source,value} @ {Wk,Wv}^T + {bk,bv}  -> Kw/Vw planes. grid 8x16x2 = 256
    gemm_f16<true, false, true><<<dim3(dk / 128, (S + 63) / 64, 2), blk, 0, stream>>>(
        srcH, srcL, wkH, wkL, nullptr, bk, bv,
        nullptr, KwH, KwL, S, dk, dllm,
        (size_t)8192000, (size_t)8388608, (size_t)1024000);

    // fused attention -> A (fp32) + Ow planes
    attn_fused<<<dim3(B * H), dim3(512), 0, stream>>>(
        QwH, QwL, KwH, KwL, VwH, VwL, mask, Aout, OwH, OwL);

    // final = Ow @ Wo^T  (B fp32, converted in-kernel). grid 32 x 64 = 2048
    gemm_f16<false, true, false><<<dim3(dllm / 128, BL / 64), blk, 0, stream>>>(
        OwH, OwL, nullptr, nullptr, Wo, nullptr, nullptr,
        outF, nullptr, nullptr, BL, dllm, dk, 0, 0, 0);
}

// Round 7
// 757.778 us; speedup vs baseline: 3.0443x; 1.0558x over previous
//
#include <hip/hip_runtime.h>

#define EPSF 1e-9f

typedef _Float16 half8 __attribute__((ext_vector_type(8)));
typedef float f32x4 __attribute__((ext_vector_type(4)));

__device__ inline void gload16(const void* gsrc, void* ldst) {
    __builtin_amdgcn_global_load_lds(
        (const __attribute__((address_space(1))) unsigned int*)gsrc,
        (__attribute__((address_space(3))) unsigned int*)ldst, 16, 0, 0);
}

// ---------------------------------------------------------------------------
// Fused pre-pass: split fp32 -> fp16 hi/lo planes for up to 7 tensors.
// ---------------------------------------------------------------------------
struct SegPack {
    const float* in[7];
    _Float16* hp[7];
    _Float16* lp[7];
    long cum[8];
    int nseg;
};

__global__ __launch_bounds__(256) void split_all(SegPack sp) {
    const long total = sp.cum[sp.nseg];
    for (long i = blockIdx.x * 256L + threadIdx.x; i < total; i += gridDim.x * 256L) {
        int s = 0;
        while (i >= sp.cum[s + 1]) ++s;
        long li = i - sp.cum[s];
        const float4* p = (const float4*)sp.in[s] + li * 2;
        float4 a = p[0], b = p[1];
        float v[8] = {a.x, a.y, a.z, a.w, b.x, b.y, b.z, b.w};
        half8 hv, lv;
#pragma unroll
        for (int k = 0; k < 8; ++k) {
            _Float16 h = (_Float16)v[k];
            hv[k] = h;
            lv[k] = (_Float16)(v[k] - (float)h);
        }
        ((half8*)sp.hp[s])[li] = hv;
        ((half8*)sp.lp[s])[li] = lv;
    }
}

// ---------------------------------------------------------------------------
// Plane GEMM: C[M,N] = (Ah+Al)(Bh+Bl)^T (+bias), 3-pass split-fp16 MFMA.
// BMx128 tile, BK=32, 256 thr = 4 waves (2x2).  Double-buffered LDS staged
// via global_load_lds(16B); T3 minimum 2-phase: stage(t+1) issued before
// MFMA(t), one barrier per K-step.  Slot-XOR swizzle (key=(r+(r>>2))&3)
// applied on the global source so ds_read_b128 fragments are <=2-way.
// ---------------------------------------------------------------------------
template <int BM, bool HAS_BIAS, bool OUT_PLANES>
__global__ __launch_bounds__(256) void gemm_planes(
    const _Float16* __restrict__ Ahp, const _Float16* __restrict__ Alp,
    const _Float16* __restrict__ Bhp, const _Float16* __restrict__ Blp,
    const float* __restrict__ bias0, const float* __restrict__ bias1,
    float* __restrict__ Cf, _Float16* __restrict__ Chp, _Float16* __restrict__ Clp,
    int M, int N, int K, long zsA, long zsB, long zsC) {
    constexpr int ABY = BM * 64;          // bytes per A plane tile (BMx32 fp16)
    constexpr int BBY = 128 * 64;         // bytes per B plane tile
    constexpr int BUF = 2 * ABY + 2 * BBY;
    constexpr int NC = (BUF / 1024) / 4;  // 1KB chunks per wave
    constexpr int MF = BM / 32;           // m-frags per wave

    __shared__ __align__(16) char lds[2 * BUF];

    const int z = blockIdx.z;
    Ahp += (long)z * zsA; Alp += (long)z * zsA;
    Bhp += (long)z * zsB; Blp += (long)z * zsB;
    if (OUT_PLANES) { Chp += (long)z * zsC; Clp += (long)z * zsC; }
    const float* bias = (HAS_BIAS && z) ? bias1 : bias0;

    const int tid = threadIdx.x;
    const int lane = tid & 63;
    const int w = tid >> 6;
    const int wm = w >> 1, wn = w & 1;
    const int fr = lane & 15, quad = lane >> 4;
    const int bm = blockIdx.y * BM;
    const int bn = blockIdx.x * 128;

    // ---- precompute per-chunk global pointers (k0 = 0) ----
    const _Float16* gptr[NC];
#pragma unroll
    for (int c = 0; c < NC; ++c) {
        const int base = (w * NC + c) * 1024;
        const _Float16* g;
        int pb;
        bool isA;
        if (base < ABY)             { g = Ahp; pb = 0;          isA = true; }
        else if (base < 2 * ABY)    { g = Alp; pb = ABY;        isA = true; }
        else if (base < 2 * ABY + BBY) { g = Bhp; pb = 2 * ABY; isA = false; }
        else                        { g = Blp; pb = 2 * ABY + BBY; isA = false; }
        int ipb = base - pb + lane * 16;
        int row = ipb >> 6;
        int slot = (ipb >> 4) & 3;
        int key = (row + (row >> 2)) & 3;
        int grow = isA ? min(bm + row, M - 1) : (bn + row);
        gptr[c] = g + (size_t)grow * K + (slot ^ key) * 8;
    }

#define STAGE(k0, bufb)                                                   \
    {                                                                     \
        _Pragma("unroll") for (int c = 0; c < NC; ++c)                    \
            gload16(gptr[c] + (k0), (bufb) + (w * NC + c) * 1024);        \
    }

    f32x4 acc[MF][4] = {};

    int cur = 0;
    STAGE(0, lds);
    __syncthreads();

    const int nt = K / 32;
    for (int t = 0; t < nt; ++t) {
        char* bufb = lds + cur * BUF;
        if (t + 1 < nt) STAGE((t + 1) * 32, lds + (cur ^ 1) * BUF);

        half8 fah[MF], fal[MF], fbh[4], fbl[4];
#pragma unroll
        for (int m = 0; m < MF; ++m) {
            int r = wm * (BM / 2) + m * 16 + fr;
            int sw = (quad ^ ((r + (r >> 2)) & 3)) * 16;
            fah[m] = *(const half8*)(bufb + r * 64 + sw);
            fal[m] = *(const half8*)(bufb + ABY + r * 64 + sw);
        }
#pragma unroll
        for (int n = 0; n < 4; ++n) {
            int c = wn * 64 + n * 16 + fr;
            int sw = (quad ^ ((c + (c >> 2)) & 3)) * 16;
            fbh[n] = *(const half8*)(bufb + 2 * ABY + c * 64 + sw);
            fbl[n] = *(const half8*)(bufb + 2 * ABY + BBY + c * 64 + sw);
        }
#pragma unroll
        for (int m = 0; m < MF; ++m)
#pragma unroll
            for (int n = 0; n < 4; ++n) {
                acc[m][n] = __builtin_amdgcn_mfma_f32_16x16x32_f16(fal[m], fbh[n], acc[m][n], 0, 0, 0);
                acc[m][n] = __builtin_amdgcn_mfma_f32_16x16x32_f16(fah[m], fbl[n], acc[m][n], 0, 0, 0);
                acc[m][n] = __builtin_amdgcn_mfma_f32_16x16x32_f16(fah[m], fbh[n], acc[m][n], 0, 0, 0);
            }
        __syncthreads();
        cur ^= 1;
    }
#undef STAGE

    // C/D layout: col = lane&15, row = (lane>>4)*4 + reg  (m89/m91)
#pragma unroll
    for (int m = 0; m < MF; ++m)
#pragma unroll
        for (int r = 0; r < 4; ++r) {
            int grow = bm + wm * (BM / 2) + m * 16 + quad * 4 + r;
            if (grow >= M) continue;
#pragma unroll
            for (int n = 0; n < 4; ++n) {
                int gcol = bn + wn * 64 + n * 16 + fr;
                float v = acc[m][n][r];
                if (HAS_BIAS) v += bias[gcol];
                if (OUT_PLANES) {
                    _Float16 hh = (_Float16)v;
                    Chp[(size_t)grow * N + gcol] = hh;
                    Clp[(size_t)grow * N + gcol] = (_Float16)(v - (float)hh);
                } else {
                    Cf[(size_t)grow * N + gcol] = v;
                }
            }
        }
}

// ---------------------------------------------------------------------------
// Fallback Wo GEMM (reg-staged, B fp32 converted in-kernel) — used only when
// ws_size is too small for Wo planes.  (Round-5 kernel, validated.)
// ---------------------------------------------------------------------------
__global__ __launch_bounds__(256, 4) void gemm_f16_bf32(
    const _Float16* __restrict__ Ahp, const _Float16* __restrict__ Alp,
    const float* __restrict__ Bf, float* __restrict__ Cf,
    int M, int N, int K) {
    __shared__ __align__(16) char lds[24576];
    const int AsHo = 0, AsLo = 4096, BsHo = 8192, BsLo = 16384;

    const int tid = threadIdx.x;
    const int lane = tid & 63;
    const int w = tid >> 6;
    const int wm = w >> 1, wn = w & 1;
    const int fr = lane & 15, quad = lane >> 4;
    const int bm = blockIdx.y * 64;
    const int bn = blockIdx.x * 128;

    const int srow = tid >> 2;
    const int sslot = tid & 3;

    f32x4 acc[2][4] = {};
    half8 sAh, sAl, sBh[2], sBl[2];

#define GLOAD(k0)                                                              \
    {                                                                          \
        int gr = min(bm + srow, M - 1);                                        \
        size_t ao = (size_t)gr * K + (k0) + sslot * 8;                         \
        sAh = *(const half8*)(Ahp + ao);                                       \
        sAl = *(const half8*)(Alp + ao);                                       \
        _Pragma("unroll") for (int it = 0; it < 2; ++it) {                     \
            size_t bo = (size_t)(bn + it * 64 + srow) * K + (k0) + sslot * 8;  \
            float4 f0 = *(const float4*)(Bf + bo);                             \
            float4 f1 = *(const float4*)(Bf + bo + 4);                         \
            float vv[8] = {f0.x, f0.y, f0.z, f0.w, f1.x, f1.y, f1.z, f1.w};    \
            half8 hv, lv;                                                      \
            _Pragma("unroll") for (int q = 0; q < 8; ++q) {                    \
                _Float16 hh = (_Float16)vv[q];                                 \
                hv[q] = hh;                                                    \
                lv[q] = (_Float16)(vv[q] - (float)hh);                         \
            }                                                                  \
            sBh[it] = hv; sBl[it] = lv;                                        \
        }                                                                      \
    }

    GLOAD(0);
    const int nt = K / 32;
    for (int t = 0; t < nt; ++t) {
        __syncthreads();
        *(half8*)(lds + AsHo + srow * 64 + sslot * 16) = sAh;
        *(half8*)(lds + AsLo + srow * 64 + sslot * 16) = sAl;
#pragma unroll
        for (int it = 0; it < 2; ++it) {
            int r = it * 64 + srow;
            *(half8*)(lds + BsHo + r * 64 + sslot * 16) = sBh[it];
            *(half8*)(lds + BsLo + r * 64 + sslot * 16) = sBl[it];
        }
        __syncthreads();
        if (t + 1 < nt) GLOAD((t + 1) * 32);

        half8 fah[2], fal[2], fbh[4], fbl[4];
#pragma unroll
        for (int m = 0; m < 2; ++m) {
            int off = (wm * 32 + m * 16 + fr) * 64 + quad * 16;
            fah[m] = *(const half8*)(lds + AsHo + off);
            fal[m] = *(const half8*)(lds + AsLo + off);
        }
#pragma unroll
        for (int n = 0; n < 4; ++n) {
            int off = (wn * 64 + n * 16 + fr) * 64 + quad * 16;
            fbh[n] = *(const half8*)(lds + BsHo + off);
            fbl[n] = *(const half8*)(lds + BsLo + off);
        }
#pragma unroll
        for (int m = 0; m < 2; ++m)
#pragma unroll
            for (int n = 0; n < 4; ++n) {
                acc[m][n] = __builtin_amdgcn_mfma_f32_16x16x32_f16(fal[m], fbh[n], acc[m][n], 0, 0, 0);
                acc[m][n] = __builtin_amdgcn_mfma_f32_16x16x32_f16(fah[m], fbl[n], acc[m][n], 0, 0, 0);
                acc[m][n] = __builtin_amdgcn_mfma_f32_16x16x32_f16(fah[m], fbh[n], acc[m][n], 0, 0, 0);
            }
    }
#undef GLOAD

#pragma unroll
    for (int m = 0; m < 2; ++m)
#pragma unroll
        for (int r = 0; r < 4; ++r) {
            int grow = bm + wm * 32 + m * 16 + quad * 4 + r;
            if (grow >= M) continue;
#pragma unroll
            for (int n = 0; n < 4; ++n) {
                int gcol = bn + wn * 64 + n * 16 + fr;
                Cf[(size_t)grow * N + gcol] = acc[m][n][r];
            }
        }
}

// ---------------------------------------------------------------------------
// Fused attention (unchanged from round 5, validated).
// ---------------------------------------------------------------------------
__global__ __launch_bounds__(512) void attn_fused(
    const _Float16* __restrict__ Qh, const _Float16* __restrict__ Ql,
    const _Float16* __restrict__ Kh, const _Float16* __restrict__ Kl,
    const _Float16* __restrict__ Vh, const _Float16* __restrict__ Vl,
    const int* __restrict__ mask,
    float* __restrict__ Aout,
    _Float16* __restrict__ Owh, _Float16* __restrict__ Owl) {
    const int S = 1000, NT = 16;

    __shared__ __align__(16) char KhL[64 * 128];
    __shared__ __align__(16) char KlL[64 * 128];
    __shared__ __align__(16) _Float16 Vth[64][72];
    __shared__ __align__(16) _Float16 Vtl[64][72];
    __shared__ __align__(16) char Pb[8 * 32 * 128];

    const int tid = threadIdx.x;
    const int lane = tid & 63;
    const int w = tid >> 6;
    const int le = lane & 15;
    const int quad = lane >> 4;
    const int bh = blockIdx.x;
    const int b = bh >> 4, h = bh & 15;

#define SWZ(row, byte) ((row) * 128 + ((byte) ^ (((row) & 7) << 4)))

    half8 qh[2][2], ql[2][2];
#pragma unroll
    for (int m = 0; m < 2; ++m)
#pragma unroll
        for (int t = 0; t < 2; ++t) {
            size_t qo = ((size_t)(b * 256 + w * 32 + m * 16 + le)) * 1024 + h * 64 + t * 32 + quad * 8;
            qh[m][t] = *(const half8*)(Qh + qo);
            ql[m][t] = *(const half8*)(Ql + qo);
        }

    int mk[2][4];
#pragma unroll
    for (int m = 0; m < 2; ++m)
#pragma unroll
        for (int r = 0; r < 4; ++r)
            mk[m][r] = mask[b * 256 + w * 32 + m * 16 + quad * 4 + r];

    const int sr = tid >> 3;
    const int sc = tid & 7;
    half8 kha, kla;
    _Float16 vvh[8], vvl[8];

#define LOADK(t)                                                       \
    {                                                                  \
        int s_ = min((t) * 64 + sr, S - 1);                            \
        size_t o_ = (size_t)s_ * 1024 + h * 64 + sc * 8;               \
        kha = *(const half8*)(Kh + o_);                                \
        kla = *(const half8*)(Kl + o_);                                \
    }
#define LOADV(t)                                                       \
    {                                                                  \
        int s_ = min((t) * 64 + sr, S - 1);                            \
        size_t o_ = (size_t)s_ * 1024 + h * 64 + sc;                   \
        _Pragma("unroll") for (int i_ = 0; i_ < 8; ++i_) {             \
            vvh[i_] = Vh[o_ + 8 * i_];                                 \
            vvl[i_] = Vl[o_ + 8 * i_];                                 \
        }                                                              \
    }
#define STOREK()                                                       \
    {                                                                  \
        *(half8*)(KhL + SWZ(sr, sc * 16)) = kha;                       \
        *(half8*)(KlL + SWZ(sr, sc * 16)) = kla;                       \
    }
#define STOREV()                                                       \
    {                                                                  \
        _Pragma("unroll") for (int i_ = 0; i_ < 8; ++i_) {             \
            Vth[sc + 8 * i_][sr] = vvh[i_];                            \
            Vtl[sc + 8 * i_][sr] = vvl[i_];                            \
        }                                                              \
    }
#define SCORES(acc)                                                           \
    _Pragma("unroll") for (int j = 0; j < 4; ++j) {                           \
        int srow_ = j * 16 + le;                                              \
        half8 kh0 = *(const half8*)(KhL + SWZ(srow_, quad * 16));             \
        half8 kh1 = *(const half8*)(KhL + SWZ(srow_, 64 + quad * 16));        \
        half8 kl0 = *(const half8*)(KlL + SWZ(srow_, quad * 16));             \
        half8 kl1 = *(const half8*)(KlL + SWZ(srow_, 64 + quad * 16));        \
        _Pragma("unroll") for (int m = 0; m < 2; ++m) {                       \
            acc[m][j] = __builtin_amdgcn_mfma_f32_16x16x32_f16(ql[m][0], kh0, acc[m][j], 0, 0, 0); \
            acc[m][j] = __builtin_amdgcn_mfma_f32_16x16x32_f16(qh[m][0], kl0, acc[m][j], 0, 0, 0); \
            acc[m][j] = __builtin_amdgcn_mfma_f32_16x16x32_f16(qh[m][0], kh0, acc[m][j], 0, 0, 0); \
            acc[m][j] = __builtin_amdgcn_mfma_f32_16x16x32_f16(ql[m][1], kh1, acc[m][j], 0, 0, 0); \
            acc[m][j] = __builtin_amdgcn_mfma_f32_16x16x32_f16(qh[m][1], kl1, acc[m][j], 0, 0, 0); \
            acc[m][j] = __builtin_amdgcn_mfma_f32_16x16x32_f16(qh[m][1], kh1, acc[m][j], 0, 0, 0); \
        }                                                                     \
    }
#define SCALEACC(acc)                                                  \
    _Pragma("unroll") for (int m = 0; m < 2; ++m)                      \
        _Pragma("unroll") for (int j = 0; j < 4; ++j) acc[m][j] *= 0.125f;

    // ================= pass 1 =================
    float mrun[2][4], lrun[2][4];
#pragma unroll
    for (int m = 0; m < 2; ++m)
#pragma unroll
        for (int r = 0; r < 4; ++r) { mrun[m][r] = -1e30f; lrun[m][r] = 0.f; }

    LOADK(0);
    for (int t = 0; t < NT; ++t) {
        __syncthreads();
        STOREK();
        __syncthreads();
        if (t + 1 < NT) LOADK(t + 1);

        f32x4 acc[2][4] = {};
        SCORES(acc);
        SCALEACC(acc);

        if (t == NT - 1) {
#pragma unroll
            for (int m = 0; m < 2; ++m)
#pragma unroll
                for (int j = 0; j < 4; ++j)
                    if (j * 16 + le >= 40) {
#pragma unroll
                        for (int r = 0; r < 4; ++r) acc[m][j][r] = -1e30f;
                    }
        }

        float tm[2][4];
#pragma unroll
        for (int m = 0; m < 2; ++m)
#pragma unroll
            for (int r = 0; r < 4; ++r)
                tm[m][r] = fmaxf(fmaxf(acc[m][0][r], acc[m][1][r]),
                                 fmaxf(acc[m][2][r], acc[m][3][r]));
#pragma unroll
        for (int xm = 1; xm < 16; xm <<= 1)
#pragma unroll
            for (int m = 0; m < 2; ++m)
#pragma unroll
                for (int r = 0; r < 4; ++r)
                    tm[m][r] = fmaxf(tm[m][r], __shfl_xor(tm[m][r], xm));

        float mn[2][4], ts[2][4];
#pragma unroll
        for (int m = 0; m < 2; ++m)
#pragma unroll
            for (int r = 0; r < 4; ++r) {
                mn[m][r] = fmaxf(mrun[m][r], tm[m][r]);
                float s = 0.f;
#pragma unroll
                for (int j = 0; j < 4; ++j) s += __expf(acc[m][j][r] - mn[m][r]);
                ts[m][r] = s;
            }
#pragma unroll
        for (int xm = 1; xm < 16; xm <<= 1)
#pragma unroll
            for (int m = 0; m < 2; ++m)
#pragma unroll
                for (int r = 0; r < 4; ++r)
                    ts[m][r] += __shfl_xor(ts[m][r], xm);
#pragma unroll
        for (int m = 0; m < 2; ++m)
#pragma unroll
            for (int r = 0; r < 4; ++r) {
                lrun[m][r] = lrun[m][r] * __expf(mrun[m][r] - mn[m][r]) + ts[m][r];
                mrun[m][r] = mn[m][r];
            }
    }

    float fac[2][4];
#pragma unroll
    for (int m = 0; m < 2; ++m)
#pragma unroll
        for (int r = 0; r < 4; ++r) {
            float inv = 1.0f / lrun[m][r];
            float s2 = lrun[m][r] * inv;
            fac[m][r] = mk[m][r] ? 0.0f : inv / (s2 + EPSF);
        }

    // ================= pass 2 =================
    f32x4 o[2][4] = {};
    char* pb = Pb + w * 32 * 128;

    LOADK(0);
    LOADV(0);
    for (int t = 0; t < NT; ++t) {
        __syncthreads();
        STOREK();
        STOREV();
        __syncthreads();
        if (t + 1 < NT) { LOADK(t + 1); LOADV(t + 1); }

        f32x4 acc[2][4] = {};
        SCORES(acc);
        SCALEACC(acc);

        const bool last = (t == NT - 1);
#pragma unroll
        for (int m = 0; m < 2; ++m)
#pragma unroll
            for (int j = 0; j < 4; ++j) {
                bool valid = !last || (j * 16 + le < 40);
#pragma unroll
                for (int r = 0; r < 4; ++r)
                    acc[m][j][r] = valid ? __expf(acc[m][j][r] - mrun[m][r]) : 0.f;
            }

#pragma unroll
        for (int m = 0; m < 2; ++m)
#pragma unroll
            for (int r = 0; r < 4; ++r) {
                float f = fac[m][r];
                size_t ro = ((size_t)bh * 256 + w * 32 + m * 16 + quad * 4 + r) * 1000 + t * 64;
#pragma unroll
                for (int j = 0; j < 4; ++j) {
                    int sl = j * 16 + le;
                    if (!last || sl < 40) Aout[ro + sl] = acc[m][j][r] * f;
                }
            }

#pragma unroll
        for (int ks = 0; ks < 2; ++ks) {
#pragma unroll
            for (int m = 0; m < 2; ++m)
#pragma unroll
                for (int jj = 0; jj < 2; ++jj) {
                    int j = ks * 2 + jj;
#pragma unroll
                    for (int r = 0; r < 4; ++r) {
                        float e = acc[m][j][r];
                        _Float16 hh = (_Float16)e;
                        _Float16 llo = (_Float16)(e - (float)hh);
                        int q = m * 16 + quad * 4 + r;
                        int sb = (jj * 16 + le) * 2;
                        *(_Float16*)(pb + SWZ(q, sb)) = hh;
                        *(_Float16*)(pb + SWZ(q, 64 + sb)) = llo;
                    }
                }
            half8 ph[2], pl[2];
#pragma unroll
            for (int m = 0; m < 2; ++m) {
                ph[m] = *(const half8*)(pb + SWZ(m * 16 + le, quad * 16));
                pl[m] = *(const half8*)(pb + SWZ(m * 16 + le, 64 + quad * 16));
            }
#pragma unroll
            for (int n = 0; n < 4; ++n) {
                const char* vb = (const char*)Vth + (n * 16 + le) * 144 + ks * 64 + quad * 16;
                const char* vc = (const char*)Vtl + (n * 16 + le) * 144 + ks * 64 + quad * 16;
                half8 vh = *(const half8*)vb;
                half8 vl = *(const half8*)vc;
#pragma unroll
                for (int m = 0; m < 2; ++m) {
                    o[m][n] = __builtin_amdgcn_mfma_f32_16x16x32_f16(pl[m], vh, o[m][n], 0, 0, 0);
                    o[m][n] = __builtin_amdgcn_mfma_f32_16x16x32_f16(ph[m], vl, o[m][n], 0, 0, 0);
                    o[m][n] = __builtin_amdgcn_mfma_f32_16x16x32_f16(ph[m], vh, o[m][n], 0, 0, 0);
                }
            }
        }
    }

#pragma unroll
    for (int m = 0; m < 2; ++m)
#pragma unroll
        for (int r = 0; r < 4; ++r) {
            float f = fac[m][r];
            size_t ro = (size_t)(b * 256 + w * 32 + m * 16 + quad * 4 + r) * 1024 + h * 64;
#pragma unroll
            for (int n = 0; n < 4; ++n) {
                float v = o[m][n][r] * f;
                _Float16 hh = (_Float16)v;
                Owh[ro + n * 16 + le] = hh;
                Owl[ro + n * 16 + le] = (_Float16)(v - (float)hh);
            }
        }
#undef SWZ
#undef LOADK
#undef LOADV
#undef STOREK
#undef STOREV
#undef SCORES
#undef SCALEACC
}

// ---------------------------------------------------------------------------
extern "C" void kernel_launch(void* const* d_in, const int* in_sizes, int n_in,
                              void* d_out, int out_size, void* d_ws, size_t ws_size,
                              hipStream_t stream) {
    const float* target = (const float*)d_in[0];
    const float* source = (const float*)d_in[1];
    const float* value  = (const float*)d_in[2];
    const int*   mask   = (const int*)d_in[3];
    const float* Wq = (const float*)d_in[4];
    const float* Wk = (const float*)d_in[5];
    const float* bk = (const float*)d_in[6];
    const float* Wv = (const float*)d_in[7];
    const float* bv = (const float*)d_in[8];
    const float* Wo = (const float*)d_in[9];

    const int B = 16, L = 256, S = 1000, H = 16;
    const int dm = 1024, dllm = 4096, dk = 1024;
    const int BL = B * L;

    const size_t need1 = (size_t)20873216 * 2;               // base planes
    const size_t need2 = (size_t)(20873216 + 8388608) * 2;   // + Wo planes
    if (ws_size < need1) return;
    const bool big = ws_size >= need2;

    _Float16* wsf = (_Float16*)d_ws;
    _Float16* QwH = wsf;
    _Float16* QwL = QwH + 4194304;
    _Float16* KwH = QwL + 4194304;
    _Float16* VwH = KwH + 1024000;
    _Float16* KwL = VwH + 1024000;
    _Float16* VwL = KwL + 1024000;
    _Float16* OwH = VwL + 1024000;
    _Float16* OwL = OwH + 4194304;
    _Float16* WoH = OwL + 4194304;   // only valid if big
    _Float16* WoL = WoH + 4194304;

    float* outF = (float*)d_out;
    float* Aout = outF + (size_t)BL * dllm;

    _Float16* scr = (_Float16*)Aout;
    _Float16* tgtH = scr;
    _Float16* tgtL = tgtH + 4194304;
    _Float16* srcH = tgtL + 4194304;
    _Float16* srcL = srcH + 4096000;
    _Float16* valH = srcL + 4096000;
    _Float16* valL = valH + 4096000;
    _Float16* wqH  = valL + 4096000;
    _Float16* wqL  = wqH + 1048576;
    _Float16* wkH  = wqL + 1048576;
    _Float16* wkL  = wkH + 4194304;
    _Float16* wvH  = wkL + 4194304;
    _Float16* wvL  = wvH + 4194304;

    // ---- fused split prepass ----
    SegPack sp;
    const float* ins[7] = {target, source, value, Wq, Wk, Wv, Wo};
    _Float16* hps[7] = {tgtH, srcH, valH, wqH, wkH, wvH, WoH};
    _Float16* lps[7] = {tgtL, srcL, valL, wqL, wkL, wvL, WoL};
    long n8s[7] = {524288, 512000, 512000, 131072, 524288, 524288, 524288};
    sp.nseg = big ? 7 : 6;
    sp.cum[0] = 0;
    for (int i = 0; i < sp.nseg; ++i) {
        sp.in[i] = ins[i]; sp.hp[i] = hps[i]; sp.lp[i] = lps[i];
        sp.cum[i + 1] = sp.cum[i] + n8s[i];
    }
    for (int i = sp.nseg; i < 7; ++i) { sp.in[i] = nullptr; sp.hp[i] = nullptr; sp.lp[i] = nullptr; }
    for (int i = sp.nseg; i < 7; ++i) sp.cum[i + 1] = sp.cum[sp.nseg];
    split_all<<<dim3(2048), dim3(256), 0, stream>>>(sp);

    // ---- Q = target @ Wq^T -> planes.  grid 8 x 32 ----
    gemm_planes<128, false, true><<<dim3(dk / 128, BL / 128), dim3(256), 0, stream>>>(
        tgtH, tgtL, wqH, wqL, nullptr, nullptr,
        nullptr, QwH, QwL, BL, dk, dm, 0, 0, 0);

    // ---- K/V fused (z=2): {source,value} @ {Wk,Wv}^T + bias.  grid 8x16x2 ----
    gemm_planes<64, true, true><<<dim3(dk / 128, 16, 2), dim3(256), 0, stream>>>(
        srcH, srcL, wkH, wkL, bk, bv,
        nullptr, KwH, KwL, S, dk, dllm,
        (long)8192000, (long)8388608, (long)1024000);

    // ---- fused attention -> A (fp32) + Ow planes ----
    attn_fused<<<dim3(B * H), dim3(512), 0, stream>>>(
        QwH, QwL, KwH, KwL, VwH, VwL, mask, Aout, OwH, OwL);

    // ---- final = Ow @ Wo^T ----
    if (big) {
        gemm_planes<128, false, false><<<dim3(dllm / 128, BL / 128), dim3(256), 0, stream>>>(
            OwH, OwL, WoH, WoL, nullptr, nullptr,
            outF, nullptr, nullptr, BL, dllm, dk, 0, 0, 0);
    } else {
        gemm_f16_bf32<<<dim3(dllm / 128, BL / 64), dim3(256), 0, stream>>>(
            OwH, OwL, Wo, outF, BL, dllm, dk);
    }
}